// Round 13
// baseline (373.902 us; speedup 1.0000x reference)
//
#include <hip/hip_runtime.h>
#include <hip/hip_bf16.h>

typedef unsigned short u16;
typedef unsigned int u32;
typedef short bf16x8 __attribute__((ext_vector_type(8)));
typedef float f32x4 __attribute__((ext_vector_type(4)));

#define DM 1024
#define SEQ 2048
#define MTOK 8192   // 4*2048
#define NQKV 3072

// 0.125 * log2(e): scores land in log2 domain -> exp2f is a single v_exp_f32
#define QSCALE 0.18033688011112042f

#define BAR() __builtin_amdgcn_s_barrier()
#define VMW(n) asm volatile("s_waitcnt vmcnt(" #n ")" ::: "memory")
#define LGKW() asm volatile("s_waitcnt lgkmcnt(0)" ::: "memory")

__device__ __forceinline__ u16 f2bf(float f) {
  union { float f; unsigned u; } a; a.f = f;
  unsigned r = a.u + 0x7FFFu + ((a.u >> 16) & 1u);
  return (u16)(r >> 16);
}

__device__ __forceinline__ u32 cvt2(float a, float b) {
  __hip_bfloat162 t = __float22bfloat162_rn(make_float2(a, b));
  u32 r; __builtin_memcpy(&r, &t, 4); return r;
}

__device__ __forceinline__ void gload_lds16(const u16* g, u16* l) {
  __builtin_amdgcn_global_load_lds(
      (const __attribute__((address_space(1))) unsigned int*)g,
      (__attribute__((address_space(3))) unsigned int*)l, 16, 0, 0);
}

// ---------------- cast x (fp32 -> bf16), vectorized ----------------
__global__ __launch_bounds__(256) void cast_x_kernel(const float* __restrict__ in,
                                                     u16* __restrict__ out) {
  int i = blockIdx.x * 256 + threadIdx.x;
  float4 v = ((const float4*)in)[i];
  ushort4 o;
  o.x = f2bf(v.x); o.y = f2bf(v.y); o.z = f2bf(v.z); o.w = f2bf(v.w);
  ((ushort4*)out)[i] = o;
}

// ---------------- transpose + cast: in [R][C] fp32 -> out [C][R] bf16 ----------------
__global__ __launch_bounds__(256) void transpose_cast_kernel(const float* __restrict__ in,
                                                             u16* __restrict__ out,
                                                             int R, int C) {
  __shared__ float tile[32][33];
  const int tx = threadIdx.x & 31, ty = threadIdx.x >> 5;
  const int r0 = blockIdx.y << 5, c0 = blockIdx.x << 5;
#pragma unroll
  for (int i = 0; i < 32; i += 8)
    tile[ty + i][tx] = in[(size_t)(r0 + ty + i) * C + (c0 + tx)];
  __syncthreads();
#pragma unroll
  for (int i = 0; i < 32; i += 8)
    out[(size_t)(c0 + ty + i) * R + (r0 + tx)] = f2bf(tile[tx][ty + i]);
}

// ========= GEMM: 128x128 tile, BK=64, depth-2 counted-vmcnt pipeline =========
template <int EPI>
__global__ __launch_bounds__(256, 2) void gemm2_kernel(
    const u16* __restrict__ A, const u16* __restrict__ Bt,
    const float* __restrict__ bias,
    u16* __restrict__ oq, u16* __restrict__ ok, u16* __restrict__ ovT,
    float* __restrict__ of, int N) {
  __shared__ alignas(16) u16 As[2][128 * 64];   // 32 KB
  __shared__ alignas(16) u16 Bs[2][128 * 64];   // 32 KB

  const int tid = threadIdx.x, lane = tid & 63, wid = tid >> 6;
  const int wr = wid >> 1, wc = wid & 1;
  const int l15 = lane & 15, l4 = lane >> 4;
  const int swz = l15 & 7;

  // XCD-chunked mapping: 8 consecutive row-panels per XCD, row varies fastest.
  const int xcd = blockIdx.x & 7, idx = blockIdx.x >> 3;
  const int row0 = ((xcd << 3) + (idx & 7)) << 7;
  const int col0 = (idx >> 3) << 7;

  const int sr = tid >> 3;                              // 0..31
  const int scsw = ((tid & 7) ^ (sr & 7)) << 3;         // swizzled chunk (u16 offset)
  const u16* asrc = A + (size_t)(row0 + sr) * 1024 + scsw;
  const u16* bsrc = Bt + (size_t)(col0 + sr) * 1024 + scsw;

  auto stage = [&](int buf, int kt) {
#pragma unroll
    for (int j = 0; j < 4; ++j)
      gload_lds16(asrc + (size_t)(j << 5) * 1024 + (kt << 6),
                  &As[buf][0] + (j << 11) + tid * 8);
#pragma unroll
    for (int j = 0; j < 4; ++j)
      gload_lds16(bsrc + (size_t)(j << 5) * 1024 + (kt << 6),
                  &Bs[buf][0] + (j << 11) + tid * 8);
  };

  f32x4 acc[4][4];
#pragma unroll
  for (int m = 0; m < 4; ++m)
#pragma unroll
    for (int n = 0; n < 4; ++n) acc[m][n] = (f32x4){0.f, 0.f, 0.f, 0.f};

  stage(0, 0);
  stage(1, 1);

  int cur = 0;
#pragma unroll 1
  for (int t = 0; t < 16; ++t) {
    if (t < 15) { VMW(8); } else { VMW(0); }   // tile t landed; t+1 stays in flight
    BAR();

    bf16x8 af[4][2], bfr[4][2];
    {
      const u16* base = &As[cur][0] + ((wr << 6) + l15) * 64;
#pragma unroll
      for (int mf = 0; mf < 4; ++mf)
#pragma unroll
        for (int ks = 0; ks < 2; ++ks)
          af[mf][ks] = *(const bf16x8*)(base + (mf << 4) * 64 + ((((ks << 2) + l4) ^ swz) << 3));
    }
    {
      const u16* base = &Bs[cur][0] + ((wc << 6) + l15) * 64;
#pragma unroll
      for (int nf = 0; nf < 4; ++nf)
#pragma unroll
        for (int ks = 0; ks < 2; ++ks)
          bfr[nf][ks] = *(const bf16x8*)(base + (nf << 4) * 64 + ((((ks << 2) + l4) ^ swz) << 3));
    }
    LGKW();            // frags in registers -> safe to overwrite buf[cur] after barrier
    BAR();
    if (t < 14) stage(cur, t + 2);   // refill the buffer we just consumed

    __builtin_amdgcn_s_setprio(1);
#pragma unroll
    for (int ks = 0; ks < 2; ++ks)
#pragma unroll
      for (int mf = 0; mf < 4; ++mf)
#pragma unroll
        for (int nf = 0; nf < 4; ++nf)
          acc[mf][nf] = __builtin_amdgcn_mfma_f32_16x16x32_bf16(af[mf][ks], bfr[nf][ks],
                                                                acc[mf][nf], 0, 0, 0);
    __builtin_amdgcn_s_setprio(0);
    cur ^= 1;
  }

#pragma unroll
  for (int nf = 0; nf < 4; ++nf) {
    const int col = col0 + (wc << 6) + (nf << 4) + l15;
    const float bv = bias[col];
    if (EPI == 0) {
      const int sel = col >> 10;
      const int h = (col & 1023) >> 6;
      const int d = col & 63;
      const float scl = (sel == 0) ? QSCALE : 1.0f;
#pragma unroll
      for (int mf = 0; mf < 4; ++mf)
#pragma unroll
        for (int r = 0; r < 4; ++r) {
          const int row = row0 + (wr << 6) + (mf << 4) + (l4 << 2) + r;
          const int bb = row >> 11, s = row & 2047;
          const u16 v = f2bf((acc[mf][nf][r] + bv) * scl);
          const int bh = (bb << 4) + h;
          if (sel == 0)      oq[((size_t)bh * SEQ + s) * 64 + d] = v;
          else if (sel == 1) ok[((size_t)bh * SEQ + s) * 64 + d] = v;
          else               ovT[((size_t)bh * 64 + d) * SEQ + s] = v;
        }
    } else {
#pragma unroll
      for (int mf = 0; mf < 4; ++mf)
#pragma unroll
        for (int r = 0; r < 4; ++r) {
          const int row = row0 + (wr << 6) + (mf << 4) + (l4 << 2) + r;
          of[(size_t)row * N + col] = acc[mf][nf][r] + bv;
        }
    }
  }
}

// ========= flash attention: persistent 2-wave blocks + atomic work queue =========
// Work item w (heavy-first): qblk j = 31 - (w>>6), bh = w&63. 64 q rows per item,
// 32 per wave. K staged in LDS (dbuf, XOR-swizzled, counted vmcnt(4)); V read
// directly from global (L2/L3-resident; its compiler waits drain the K staging).
// LDS = 20 KB -> 8 blocks/CU (16 waves). Dynamic LPT: blocks pull items until empty.
__global__ __launch_bounds__(128, 4) void attn_kernel(const u16* __restrict__ qb,
                                                      const u16* __restrict__ kbuf,
                                                      const u16* __restrict__ vT,
                                                      u16* __restrict__ zb,
                                                      u32* __restrict__ counter) {
  __shared__ alignas(16) u16 Ks[2][64 * 64];   // 16 KB
  __shared__ alignas(16) u16 Ps[2][16 * 64];   // 4 KB
  __shared__ u32 witem;

  const int tid = threadIdx.x;
  const int lane = tid & 63, wid = tid >> 6;    // wid 0..1
  const int l15 = lane & 15, l4 = lane >> 4;
  const int swz = l15 & 7;

  const int srow = tid >> 3;                                // 0..15
  const int schk = ((tid & 7) ^ (srow & 7)) << 3;           // pre-swizzled source chunk
  u16* pw = &Ps[wid][0];

  const short osv = (short)0x3F80;
  const bf16x8 onesf = {osv, osv, osv, osv, osv, osv, osv, osv};

#pragma unroll 1
  for (;;) {
    if (tid == 0) witem = atomicAdd(counter, 1u);
    __syncthreads();
    const u32 w = witem;
    __syncthreads();
    if (w >= 2048u) return;

    const int j = 31 - (int)(w >> 6);          // heavy items first (LPT)
    const int bh = (int)(w & 63u);
    const int b = bh >> 4, h = bh & 15;

    const u16* qp = qb + (size_t)bh * SEQ * 64;
    const u16* kp = kbuf + (size_t)bh * SEQ * 64;
    const u16* vp = vT + (size_t)bh * 64 * SEQ;
    const u16* ksrc = kp + (size_t)srow * 64 + schk;

    const int qw0 = (j << 6) + (wid << 5);     // this wave's first q row
    const int nkt = j + 1;

    // Q fragments (registers); keepalive forces the wait out of the tile loop
    bf16x8 aq[2][2];
#pragma unroll
    for (int m = 0; m < 2; ++m)
#pragma unroll
      for (int c = 0; c < 2; ++c)
        aq[m][c] = *(const bf16x8*)(qp + (size_t)(qw0 + (m << 4) + l15) * 64 + (c << 5) + (l4 << 3));
    asm volatile("" :: "v"(aq[0][0]), "v"(aq[0][1]), "v"(aq[1][0]), "v"(aq[1][1]));

    f32x4 zo[2][5];
    float mrun[2] = {-INFINITY, -INFINITY};
#pragma unroll
    for (int m = 0; m < 2; ++m)
#pragma unroll
      for (int d = 0; d < 5; ++d) zo[m][d] = (f32x4){0.f, 0.f, 0.f, 0.f};

    // stage K tile (64x64): 4 loads/thread, rows srow+16*jj, linear dest
    auto stage = [&](int buf, int kt) {
#pragma unroll
      for (int jj = 0; jj < 4; ++jj)
        gload_lds16(ksrc + (size_t)kt * 4096 + (jj << 10),
                    &Ks[buf][0] + (jj << 10) + tid * 8);
    };

    stage(0, 0);
    stage(1, 1);           // kt=1 read is harmless when nkt==1 (rows exist)

    int cur = 0;
#pragma unroll 1
    for (int kt = 0; kt < nkt; ++kt) {
      if (kt + 1 < nkt) { VMW(4); } else { VMW(0); }   // tile t landed; t+1 in flight
      BAR();

      const int k0 = kt << 6;
      // ---- V fragments straight from global (L2-hit; waits also drain staging) ----
      bf16x8 vf[4][2];
#pragma unroll
      for (int d = 0; d < 4; ++d) {
        const u16* vr = vp + (size_t)((d << 4) + l15) * SEQ + k0 + (l4 << 3);
        vf[d][0] = *(const bf16x8*)(vr);
        vf[d][1] = *(const bf16x8*)(vr + 32);
      }
      // ---- QK^T (swapped): S^T[k][q], q = l15 ----
      const u16* kb_ = &Ks[cur][0];
      f32x4 s[2][4];
#pragma unroll
      for (int m = 0; m < 2; ++m)
#pragma unroll
        for (int nf = 0; nf < 4; ++nf) s[m][nf] = (f32x4){0.f, 0.f, 0.f, 0.f};
#pragma unroll
      for (int nf = 0; nf < 4; ++nf) {
        const u16* kr = kb_ + ((nf << 4) + l15) * 64;
        const bf16x8 kf0 = *(const bf16x8*)(kr + ((l4 ^ swz) << 3));
        const bf16x8 kf1 = *(const bf16x8*)(kr + (((l4 + 4) ^ swz) << 3));
#pragma unroll
        for (int m = 0; m < 2; ++m) {
          s[m][nf] = __builtin_amdgcn_mfma_f32_16x16x32_bf16(kf0, aq[m][0], s[m][nf], 0, 0, 0);
          s[m][nf] = __builtin_amdgcn_mfma_f32_16x16x32_bf16(kf1, aq[m][1], s[m][nf], 0, 0, 0);
        }
      }
      // ---- causal mask on the diagonal (last) tile ----
      if (kt == nkt - 1) {
#pragma unroll
        for (int m = 0; m < 2; ++m) {
          const int qtok = qw0 + (m << 4) + l15;
#pragma unroll
          for (int nf = 0; nf < 4; ++nf)
#pragma unroll
            for (int r = 0; r < 4; ++r) {
              const int ktok = k0 + (nf << 4) + (l4 << 2) + r;
              if (ktok > qtok) s[m][nf][r] = -INFINITY;
            }
        }
      }
      // ---- online softmax per m-half; P buffer reused between halves ----
      bf16x8 pa[2][2];
#pragma unroll
      for (int m = 0; m < 2; ++m) {
        float mx = s[m][0][0];
#pragma unroll
        for (int nf = 0; nf < 4; ++nf)
#pragma unroll
          for (int r = 0; r < 4; ++r) mx = fmaxf(mx, s[m][nf][r]);
        mx = fmaxf(mx, __shfl_xor(mx, 16));
        mx = fmaxf(mx, __shfl_xor(mx, 32));
        if (__ballot(mx > mrun[m])) {   // exact defer: skip when row max unchanged
          const float mnew = fmaxf(mrun[m], mx);
          const float alpha = exp2f(mrun[m] - mnew);
          mrun[m] = mnew;
#pragma unroll
          for (int d = 0; d < 5; ++d) zo[m][d] *= alpha;
        }
#pragma unroll
        for (int nf = 0; nf < 4; ++nf) {
          f32x4 p;
#pragma unroll
          for (int r = 0; r < 4; ++r) p[r] = exp2f(s[m][nf][r] - mrun[m]);
          const int phys = ((nf << 1) + (l4 >> 1)) ^ swz;
          uint2 o; o.x = cvt2(p[0], p[1]); o.y = cvt2(p[2], p[3]);
          *(uint2*)(pw + l15 * 64 + phys * 8 + ((l4 & 1) << 2)) = o;   // ds_write_b64
        }
#pragma unroll
        for (int c = 0; c < 2; ++c) {
          const int phys = ((c << 2) + l4) ^ swz;
          pa[m][c] = *(const bf16x8*)(pw + l15 * 64 + phys * 8);
        }
      }
      // ---- PV (V from global regs) + ones-frag row-sum ----
#pragma unroll
      for (int d = 0; d < 4; ++d) {
        zo[0][d] = __builtin_amdgcn_mfma_f32_16x16x32_bf16(vf[d][0], pa[0][0], zo[0][d], 0, 0, 0);
        zo[0][d] = __builtin_amdgcn_mfma_f32_16x16x32_bf16(vf[d][1], pa[0][1], zo[0][d], 0, 0, 0);
        zo[1][d] = __builtin_amdgcn_mfma_f32_16x16x32_bf16(vf[d][0], pa[1][0], zo[1][d], 0, 0, 0);
        zo[1][d] = __builtin_amdgcn_mfma_f32_16x16x32_bf16(vf[d][1], pa[1][1], zo[1][d], 0, 0, 0);
      }
      zo[0][4] = __builtin_amdgcn_mfma_f32_16x16x32_bf16(onesf, pa[0][0], zo[0][4], 0, 0, 0);
      zo[0][4] = __builtin_amdgcn_mfma_f32_16x16x32_bf16(onesf, pa[0][1], zo[0][4], 0, 0, 0);
      zo[1][4] = __builtin_amdgcn_mfma_f32_16x16x32_bf16(onesf, pa[1][0], zo[1][4], 0, 0, 0);
      zo[1][4] = __builtin_amdgcn_mfma_f32_16x16x32_bf16(onesf, pa[1][1], zo[1][4], 0, 0, 0);

      BAR();
      if (kt + 2 < nkt) stage(cur, kt + 2);   // refill the buffer we just consumed
      cur ^= 1;
    }

    // ---- epilogue: every lane holds its q's denominator in zo[m][4][0] ----
#pragma unroll
    for (int m = 0; m < 2; ++m) {
      const float inv = 1.0f / zo[m][4][0];
      const int q = qw0 + (m << 4) + l15;
#pragma unroll
      for (int d = 0; d < 4; ++d) {
        uint2 o;
        o.x = cvt2(zo[m][d][0] * inv, zo[m][d][1] * inv);
        o.y = cvt2(zo[m][d][2] * inv, zo[m][d][3] * inv);
        *(uint2*)(zb + (((size_t)b * SEQ + q) * 16 + h) * 64 + (d << 4) + (l4 << 2)) = o;
      }
    }
    __syncthreads();   // all reads of witem done before next item's write
  }
}

// ---------------- launch ----------------
extern "C" void kernel_launch(void* const* d_in, const int* in_sizes, int n_in,
                              void* d_out, int out_size, void* d_ws, size_t ws_size,
                              hipStream_t stream) {
  const float* x     = (const float*)d_in[0];
  const float* w_qkv = (const float*)d_in[1];
  const float* b_qkv = (const float*)d_in[2];
  const float* w_out = (const float*)d_in[3];
  const float* b_out = (const float*)d_in[4];
  float* out = (float*)d_out;

  char* ws = (char*)d_ws;
  u16* xb    = (u16*)ws;  ws += (size_t)MTOK * DM * 2;
  u16* wqkvT = (u16*)ws;  ws += (size_t)NQKV * DM * 2;
  u16* woutT = (u16*)ws;  ws += (size_t)DM * DM * 2;
  u16* qb    = (u16*)ws;  ws += (size_t)MTOK * DM * 2;
  u16* kb    = (u16*)ws;  ws += (size_t)MTOK * DM * 2;
  u16* vTb   = (u16*)ws;  ws += (size_t)MTOK * DM * 2;
  u16* zbuf  = (u16*)ws;  ws += (size_t)MTOK * DM * 2;
  u32* counter = (u32*)ws;

  hipMemsetAsync(counter, 0, 4, stream);

  cast_x_kernel<<<MTOK * DM / 1024, 256, 0, stream>>>(x, xb);
  transpose_cast_kernel<<<dim3(NQKV / 32, DM / 32), 256, 0, stream>>>(w_qkv, wqkvT, DM, NQKV);
  transpose_cast_kernel<<<dim3(DM / 32, DM / 32), 256, 0, stream>>>(w_out, woutT, DM, DM);

  gemm2_kernel<0><<<1536, 256, 0, stream>>>(xb, wqkvT, b_qkv, qb, kb, vTb, nullptr, NQKV);

  attn_kernel<<<2048, 128, 0, stream>>>(qb, kb, vTb, zbuf, counter);

  gemm2_kernel<1><<<512, 256, 0, stream>>>(zbuf, woutT, b_out, nullptr, nullptr, nullptr, out, DM);
}

// Round 14
// 192.273 us; speedup vs baseline: 1.9446x; 1.9446x over previous
//
#include <hip/hip_runtime.h>
#include <hip/hip_bf16.h>

typedef unsigned short u16;
typedef unsigned int u32;
typedef short bf16x8 __attribute__((ext_vector_type(8)));
typedef float f32x4 __attribute__((ext_vector_type(4)));

#define DM 1024
#define SEQ 2048
#define MTOK 8192   // 4*2048
#define NQKV 3072

// 0.125 * log2(e): scores land in log2 domain -> exp2f is a single v_exp_f32
#define QSCALE 0.18033688011112042f

#define BAR() __builtin_amdgcn_s_barrier()
#define VMW(n) asm volatile("s_waitcnt vmcnt(" #n ")" ::: "memory")
#define LGKW() asm volatile("s_waitcnt lgkmcnt(0)" ::: "memory")

__device__ __forceinline__ u16 f2bf(float f) {
  union { float f; unsigned u; } a; a.f = f;
  unsigned r = a.u + 0x7FFFu + ((a.u >> 16) & 1u);
  return (u16)(r >> 16);
}

__device__ __forceinline__ u32 cvt2(float a, float b) {
  __hip_bfloat162 t = __float22bfloat162_rn(make_float2(a, b));
  u32 r; __builtin_memcpy(&r, &t, 4); return r;
}

__device__ __forceinline__ void gload_lds16(const u16* g, u16* l) {
  __builtin_amdgcn_global_load_lds(
      (const __attribute__((address_space(1))) unsigned int*)g,
      (__attribute__((address_space(3))) unsigned int*)l, 16, 0, 0);
}

// ---------------- cast x (fp32 -> bf16), vectorized ----------------
__global__ __launch_bounds__(256) void cast_x_kernel(const float* __restrict__ in,
                                                     u16* __restrict__ out) {
  int i = blockIdx.x * 256 + threadIdx.x;
  float4 v = ((const float4*)in)[i];
  ushort4 o;
  o.x = f2bf(v.x); o.y = f2bf(v.y); o.z = f2bf(v.z); o.w = f2bf(v.w);
  ((ushort4*)out)[i] = o;
}

// ---------------- transpose + cast: in [R][C] fp32 -> out [C][R] bf16 ----------------
__global__ __launch_bounds__(256) void transpose_cast_kernel(const float* __restrict__ in,
                                                             u16* __restrict__ out,
                                                             int R, int C) {
  __shared__ float tile[32][33];
  const int tx = threadIdx.x & 31, ty = threadIdx.x >> 5;
  const int r0 = blockIdx.y << 5, c0 = blockIdx.x << 5;
#pragma unroll
  for (int i = 0; i < 32; i += 8)
    tile[ty + i][tx] = in[(size_t)(r0 + ty + i) * C + (c0 + tx)];
  __syncthreads();
#pragma unroll
  for (int i = 0; i < 32; i += 8)
    out[(size_t)(c0 + ty + i) * R + (r0 + tx)] = f2bf(tile[tx][ty + i]);
}

// ========= GEMM: 128x128 tile, BK=64, depth-2 counted-vmcnt pipeline =========
template <int EPI>
__global__ __launch_bounds__(256, 2) void gemm2_kernel(
    const u16* __restrict__ A, const u16* __restrict__ Bt,
    const float* __restrict__ bias,
    u16* __restrict__ oq, u16* __restrict__ ok, u16* __restrict__ ovT,
    float* __restrict__ of, int N) {
  __shared__ alignas(16) u16 As[2][128 * 64];   // 32 KB
  __shared__ alignas(16) u16 Bs[2][128 * 64];   // 32 KB

  const int tid = threadIdx.x, lane = tid & 63, wid = tid >> 6;
  const int wr = wid >> 1, wc = wid & 1;
  const int l15 = lane & 15, l4 = lane >> 4;
  const int swz = l15 & 7;

  // XCD-chunked mapping: 8 consecutive row-panels per XCD, row varies fastest.
  const int xcd = blockIdx.x & 7, idx = blockIdx.x >> 3;
  const int row0 = ((xcd << 3) + (idx & 7)) << 7;
  const int col0 = (idx >> 3) << 7;

  const int sr = tid >> 3;                              // 0..31
  const int scsw = ((tid & 7) ^ (sr & 7)) << 3;         // swizzled chunk (u16 offset)
  const u16* asrc = A + (size_t)(row0 + sr) * 1024 + scsw;
  const u16* bsrc = Bt + (size_t)(col0 + sr) * 1024 + scsw;

  auto stage = [&](int buf, int kt) {
#pragma unroll
    for (int j = 0; j < 4; ++j)
      gload_lds16(asrc + (size_t)(j << 5) * 1024 + (kt << 6),
                  &As[buf][0] + (j << 11) + tid * 8);
#pragma unroll
    for (int j = 0; j < 4; ++j)
      gload_lds16(bsrc + (size_t)(j << 5) * 1024 + (kt << 6),
                  &Bs[buf][0] + (j << 11) + tid * 8);
  };

  f32x4 acc[4][4];
#pragma unroll
  for (int m = 0; m < 4; ++m)
#pragma unroll
    for (int n = 0; n < 4; ++n) acc[m][n] = (f32x4){0.f, 0.f, 0.f, 0.f};

  stage(0, 0);
  stage(1, 1);

  int cur = 0;
#pragma unroll 1
  for (int t = 0; t < 16; ++t) {
    if (t < 15) { VMW(8); } else { VMW(0); }   // tile t landed; t+1 stays in flight
    BAR();

    bf16x8 af[4][2], bfr[4][2];
    {
      const u16* base = &As[cur][0] + ((wr << 6) + l15) * 64;
#pragma unroll
      for (int mf = 0; mf < 4; ++mf)
#pragma unroll
        for (int ks = 0; ks < 2; ++ks)
          af[mf][ks] = *(const bf16x8*)(base + (mf << 4) * 64 + ((((ks << 2) + l4) ^ swz) << 3));
    }
    {
      const u16* base = &Bs[cur][0] + ((wc << 6) + l15) * 64;
#pragma unroll
      for (int nf = 0; nf < 4; ++nf)
#pragma unroll
        for (int ks = 0; ks < 2; ++ks)
          bfr[nf][ks] = *(const bf16x8*)(base + (nf << 4) * 64 + ((((ks << 2) + l4) ^ swz) << 3));
    }
    LGKW();            // frags in registers -> safe to overwrite buf[cur] after barrier
    BAR();
    if (t < 14) stage(cur, t + 2);   // refill the buffer we just consumed

    __builtin_amdgcn_s_setprio(1);
#pragma unroll
    for (int ks = 0; ks < 2; ++ks)
#pragma unroll
      for (int mf = 0; mf < 4; ++mf)
#pragma unroll
        for (int nf = 0; nf < 4; ++nf)
          acc[mf][nf] = __builtin_amdgcn_mfma_f32_16x16x32_bf16(af[mf][ks], bfr[nf][ks],
                                                                acc[mf][nf], 0, 0, 0);
    __builtin_amdgcn_s_setprio(0);
    cur ^= 1;
  }

#pragma unroll
  for (int nf = 0; nf < 4; ++nf) {
    const int col = col0 + (wc << 6) + (nf << 4) + l15;
    const float bv = bias[col];
    if (EPI == 0) {
      const int sel = col >> 10;
      const int h = (col & 1023) >> 6;
      const int d = col & 63;
      const float scl = (sel == 0) ? QSCALE : 1.0f;
#pragma unroll
      for (int mf = 0; mf < 4; ++mf)
#pragma unroll
        for (int r = 0; r < 4; ++r) {
          const int row = row0 + (wr << 6) + (mf << 4) + (l4 << 2) + r;
          const int bb = row >> 11, s = row & 2047;
          const u16 v = f2bf((acc[mf][nf][r] + bv) * scl);
          const int bh = (bb << 4) + h;
          if (sel == 0)      oq[((size_t)bh * SEQ + s) * 64 + d] = v;
          else if (sel == 1) ok[((size_t)bh * SEQ + s) * 64 + d] = v;
          else               ovT[((size_t)bh * 64 + d) * SEQ + s] = v;
        }
    } else {
#pragma unroll
      for (int mf = 0; mf < 4; ++mf)
#pragma unroll
        for (int r = 0; r < 4; ++r) {
          const int row = row0 + (wr << 6) + (mf << 4) + (l4 << 2) + r;
          of[(size_t)row * N + col] = acc[mf][nf][r] + bv;
        }
    }
  }
}

// ========= flash attention: 4 waves/block (128 q rows), 40 KB LDS, 4 blocks/CU =========
// R12 structure. qpart -> qseg uses a balanced table: each CU's 4 resident blocks
// (qparts {p, p+4, p+8, p+12}) get qsegs summing to a constant 30 -> per-CU k-tile
// totals are equal (34), removing the 40/36/32/28 static imbalance measured in R12.
__global__ __launch_bounds__(256, 4) void attn_kernel(const u16* __restrict__ qb,
                                                      const u16* __restrict__ kbuf,
                                                      const u16* __restrict__ vT,
                                                      u16* __restrict__ zb) {
  __shared__ alignas(16) u16 Ks[2][64 * 64];   // 16 KB
  __shared__ alignas(16) u16 Vs[2][64 * 64];   // 16 KB
  __shared__ alignas(16) u16 Ps[4][16 * 64];   // 8 KB
  // total 40 KB -> 4 blocks/CU

  const int bid = blockIdx.x;
  const int xcd = bid & 7;
  const int idx = bid >> 3;                     // 0..127
  const int bh = (xcd << 3) | (idx & 7);        // 8 bh per XCD
  const int qpart = idx >> 3;                   // 0..15
  // balanced qseg table: class r = qpart&3, slot i = qpart>>2
  //   r0:{15,8,4,3} r1:{14,9,5,2} r2:{13,10,6,1} r3:{12,11,7,0}  (bijective on 0..15)
  const u32 qtab[4] = {0x0304080Fu, 0x0205090Eu, 0x01060A0Du, 0x00070B0Cu};
  const int qseg = (int)((qtab[qpart & 3] >> ((qpart >> 2) << 3)) & 15u);
  const int b = bh >> 4, h = bh & 15;

  const int tid = threadIdx.x;
  const int lane = tid & 63, wid = tid >> 6;    // wid 0..3
  const int l15 = lane & 15, l4 = lane >> 4;
  const int swz = l15 & 7;

  const u16* qp = qb + (size_t)bh * SEQ * 64;
  const u16* kp = kbuf + (size_t)bh * SEQ * 64;
  const u16* vp = vT + (size_t)bh * 64 * SEQ;

  const int qw0 = (qseg << 7) + (wid << 5);     // this wave's first q row
  const int nkt = (qseg + 1) << 1;              // block k-tiles (>= 2)
  const int ktmax = (qseg << 1) + (wid >> 1);   // this wave's diagonal tile

  // staging: 2 K rows + 2 V rows per thread per tile (rows r and r+32), uniform 4 loads
  const int srow = tid >> 3;                                  // 0..31
  const int schk = ((tid & 7) ^ (srow & 7)) << 3;             // pre-swizzled source chunk
  const u16* ksrc = kp + (size_t)srow * 64 + schk;
  const u16* vsrc = vp + (size_t)srow * SEQ + schk;

  auto stage = [&](int buf, int kt) {
    gload_lds16(ksrc + (size_t)kt * 4096, &Ks[buf][0] + tid * 8);
    gload_lds16(ksrc + (size_t)kt * 4096 + 32 * 64, &Ks[buf][0] + 2048 + tid * 8);
    gload_lds16(vsrc + (size_t)kt * 64, &Vs[buf][0] + tid * 8);
    gload_lds16(vsrc + (size_t)kt * 64 + (size_t)32 * SEQ, &Vs[buf][0] + 2048 + tid * 8);
  };

  // Q fragments (registers, once); keepalive forces the wait into the preheader
  bf16x8 aq[2][2];
#pragma unroll
  for (int m = 0; m < 2; ++m)
#pragma unroll
    for (int c = 0; c < 2; ++c)
      aq[m][c] = *(const bf16x8*)(qp + (size_t)(qw0 + (m << 4) + l15) * 64 + (c << 5) + (l4 << 3));
  asm volatile("" :: "v"(aq[0][0]), "v"(aq[0][1]), "v"(aq[1][0]), "v"(aq[1][1]));

  // constant all-ones A-fragment: mfma(ones, P) -> every D row = column-sum of P
  const short osv = (short)0x3F80;
  const bf16x8 onesf = {osv, osv, osv, osv, osv, osv, osv, osv};

  f32x4 zo[2][5];
  float mrun[2] = {-INFINITY, -INFINITY};
#pragma unroll
  for (int m = 0; m < 2; ++m)
#pragma unroll
    for (int d = 0; d < 5; ++d) zo[m][d] = (f32x4){0.f, 0.f, 0.f, 0.f};

  u16* pw = &Ps[wid][0];

  stage(0, 0);
  stage(1, 1);

  int cur = 0;
#pragma unroll 1
  for (int kt = 0; kt < nkt; ++kt) {
    if (kt + 1 < nkt) { VMW(4); } else { VMW(0); }   // tile t landed; t+1 in flight
    BAR();

    if (kt <= ktmax) {
      const int k0 = kt << 6;
      const u16* kb_ = &Ks[cur][0];
      const u16* vb_ = &Vs[cur][0];
      // ---- QK^T (swapped): S^T[k][q], q = l15 ----
      f32x4 s[2][4];
#pragma unroll
      for (int m = 0; m < 2; ++m)
#pragma unroll
        for (int nf = 0; nf < 4; ++nf) s[m][nf] = (f32x4){0.f, 0.f, 0.f, 0.f};
#pragma unroll
      for (int nf = 0; nf < 4; ++nf) {
        const u16* kr = kb_ + ((nf << 4) + l15) * 64;
        const bf16x8 kf0 = *(const bf16x8*)(kr + ((l4 ^ swz) << 3));
        const bf16x8 kf1 = *(const bf16x8*)(kr + (((l4 + 4) ^ swz) << 3));
#pragma unroll
        for (int m = 0; m < 2; ++m) {
          s[m][nf] = __builtin_amdgcn_mfma_f32_16x16x32_bf16(kf0, aq[m][0], s[m][nf], 0, 0, 0);
          s[m][nf] = __builtin_amdgcn_mfma_f32_16x16x32_bf16(kf1, aq[m][1], s[m][nf], 0, 0, 0);
        }
      }
      // ---- causal mask on this wave's diagonal tile ----
      if (kt == ktmax) {
#pragma unroll
        for (int m = 0; m < 2; ++m) {
          const int qtok = qw0 + (m << 4) + l15;
#pragma unroll
          for (int nf = 0; nf < 4; ++nf)
#pragma unroll
            for (int r = 0; r < 4; ++r) {
              const int ktok = k0 + (nf << 4) + (l4 << 2) + r;
              if (ktok > qtok) s[m][nf][r] = -INFINITY;
            }
        }
      }
      // ---- online softmax per m-half; P buffer reused between halves ----
      bf16x8 pa[2][2];
#pragma unroll
      for (int m = 0; m < 2; ++m) {
        float mx = s[m][0][0];
#pragma unroll
        for (int nf = 0; nf < 4; ++nf)
#pragma unroll
          for (int r = 0; r < 4; ++r) mx = fmaxf(mx, s[m][nf][r]);
        mx = fmaxf(mx, __shfl_xor(mx, 16));
        mx = fmaxf(mx, __shfl_xor(mx, 32));
        if (__ballot(mx > mrun[m])) {   // exact defer: skip when row max unchanged
          const float mnew = fmaxf(mrun[m], mx);
          const float alpha = exp2f(mrun[m] - mnew);
          mrun[m] = mnew;
#pragma unroll
          for (int d = 0; d < 5; ++d) zo[m][d] *= alpha;
        }
#pragma unroll
        for (int nf = 0; nf < 4; ++nf) {
          f32x4 p;
#pragma unroll
          for (int r = 0; r < 4; ++r) p[r] = exp2f(s[m][nf][r] - mrun[m]);
          const int phys = ((nf << 1) + (l4 >> 1)) ^ swz;
          uint2 o; o.x = cvt2(p[0], p[1]); o.y = cvt2(p[2], p[3]);
          *(uint2*)(pw + l15 * 64 + phys * 8 + ((l4 & 1) << 2)) = o;   // ds_write_b64
        }
        // read this half's P fragments (swizzled, conflict-spread)
#pragma unroll
        for (int c = 0; c < 2; ++c) {
          const int phys = ((c << 2) + l4) ^ swz;
          pa[m][c] = *(const bf16x8*)(pw + l15 * 64 + phys * 8);
        }
      }
      // ---- PV: per-d V reads (transient regs) + ones-frag row-sum ----
#pragma unroll
      for (int d = 0; d < 4; ++d) {
        const u16* vr = vb_ + ((d << 4) + l15) * 64;
        const bf16x8 vf0 = *(const bf16x8*)(vr + ((l4 ^ swz) << 3));
        const bf16x8 vf1 = *(const bf16x8*)(vr + (((l4 + 4) ^ swz) << 3));
        zo[0][d] = __builtin_amdgcn_mfma_f32_16x16x32_bf16(vf0, pa[0][0], zo[0][d], 0, 0, 0);
        zo[0][d] = __builtin_amdgcn_mfma_f32_16x16x32_bf16(vf1, pa[0][1], zo[0][d], 0, 0, 0);
        zo[1][d] = __builtin_amdgcn_mfma_f32_16x16x32_bf16(vf0, pa[1][0], zo[1][d], 0, 0, 0);
        zo[1][d] = __builtin_amdgcn_mfma_f32_16x16x32_bf16(vf1, pa[1][1], zo[1][d], 0, 0, 0);
      }
      zo[0][4] = __builtin_amdgcn_mfma_f32_16x16x32_bf16(onesf, pa[0][0], zo[0][4], 0, 0, 0);
      zo[0][4] = __builtin_amdgcn_mfma_f32_16x16x32_bf16(onesf, pa[0][1], zo[0][4], 0, 0, 0);
      zo[1][4] = __builtin_amdgcn_mfma_f32_16x16x32_bf16(onesf, pa[1][0], zo[1][4], 0, 0, 0);
      zo[1][4] = __builtin_amdgcn_mfma_f32_16x16x32_bf16(onesf, pa[1][1], zo[1][4], 0, 0, 0);
    }

    BAR();
    if (kt + 2 < nkt) stage(cur, kt + 2);   // refill the buffer we just consumed
    cur ^= 1;
  }

  // ---- epilogue: every lane holds its q's denominator in zo[m][4][0] ----
#pragma unroll
  for (int m = 0; m < 2; ++m) {
    const float inv = 1.0f / zo[m][4][0];
    const int q = qw0 + (m << 4) + l15;
#pragma unroll
    for (int d = 0; d < 4; ++d) {
      uint2 o;
      o.x = cvt2(zo[m][d][0] * inv, zo[m][d][1] * inv);
      o.y = cvt2(zo[m][d][2] * inv, zo[m][d][3] * inv);
      *(uint2*)(zb + (((size_t)b * SEQ + q) * 16 + h) * 64 + (d << 4) + (l4 << 2)) = o;
    }
  }
}

// ---------------- launch ----------------
extern "C" void kernel_launch(void* const* d_in, const int* in_sizes, int n_in,
                              void* d_out, int out_size, void* d_ws, size_t ws_size,
                              hipStream_t stream) {
  const float* x     = (const float*)d_in[0];
  const float* w_qkv = (const float*)d_in[1];
  const float* b_qkv = (const float*)d_in[2];
  const float* w_out = (const float*)d_in[3];
  const float* b_out = (const float*)d_in[4];
  float* out = (float*)d_out;

  char* ws = (char*)d_ws;
  u16* xb    = (u16*)ws;  ws += (size_t)MTOK * DM * 2;
  u16* wqkvT = (u16*)ws;  ws += (size_t)NQKV * DM * 2;
  u16* woutT = (u16*)ws;  ws += (size_t)DM * DM * 2;
  u16* qb    = (u16*)ws;  ws += (size_t)MTOK * DM * 2;
  u16* kb    = (u16*)ws;  ws += (size_t)MTOK * DM * 2;
  u16* vTb   = (u16*)ws;  ws += (size_t)MTOK * DM * 2;
  u16* zbuf  = (u16*)ws;  ws += (size_t)MTOK * DM * 2;

  cast_x_kernel<<<MTOK * DM / 1024, 256, 0, stream>>>(x, xb);
  transpose_cast_kernel<<<dim3(NQKV / 32, DM / 32), 256, 0, stream>>>(w_qkv, wqkvT, DM, NQKV);
  transpose_cast_kernel<<<dim3(DM / 32, DM / 32), 256, 0, stream>>>(w_out, woutT, DM, DM);

  gemm2_kernel<0><<<1536, 256, 0, stream>>>(xb, wqkvT, b_qkv, qb, kb, vTb, nullptr, NQKV);

  attn_kernel<<<1024, 256, 0, stream>>>(qb, kb, vTb, zbuf);

  gemm2_kernel<1><<<512, 256, 0, stream>>>(zbuf, woutT, b_out, nullptr, nullptr, nullptr, out, DM);
}